// Round 1
// baseline (430.592 us; speedup 1.0000x reference)
//
#include <hip/hip_runtime.h>

typedef _Float16 f16;
typedef __attribute__((ext_vector_type(8))) _Float16 f16x8;
typedef __attribute__((ext_vector_type(4))) float f32x4;

#define B_ 8192
#define D_ 784
#define H_ 1024
#define L_ 128
#define T_ 10
#define KP1 832          // D padded to multiple of 64
#define NPH 896          // head N padded to multiple of 128
#define MAXTILES (B_/128 + T_)   // 74

// ctrl int indices
#define C_COUNT 0
#define C_CURS 16
#define C_OFFS 32        // 17 entries
#define C_NTILES 49
#define C_TTASK 64       // 80 entries
#define C_TROW 160       // 80 entries

__global__ void k_init(int* ctrl) {
    if (threadIdx.x < 64) ctrl[threadIdx.x] = 0;
}

__global__ void k_count(const int* __restrict__ task, int* __restrict__ ctrl) {
    int b = blockIdx.x * 256 + threadIdx.x;
    if (b < B_) atomicAdd(&ctrl[C_COUNT + task[b]], 1);
}

__global__ void k_scan(int* ctrl) {
    if (threadIdx.x == 0 && blockIdx.x == 0) {
        int off = 0;
        ctrl[C_OFFS] = 0;
        for (int t = 0; t < T_; ++t) { off += ctrl[C_COUNT + t]; ctrl[C_OFFS + t + 1] = off; }
        int nt = 0;
        for (int t = 0; t < T_; ++t) {
            for (int r = ctrl[C_OFFS + t]; r < ctrl[C_OFFS + t + 1]; r += 128) {
                ctrl[C_TTASK + nt] = t;
                ctrl[C_TROW + nt] = r;
                ++nt;
            }
        }
        ctrl[C_NTILES] = nt;
    }
}

__global__ void k_scatter(const int* __restrict__ task, int* __restrict__ ctrl, int* __restrict__ perm) {
    int b = blockIdx.x * 256 + threadIdx.x;
    if (b >= B_) return;
    int t = task[b];
    int i = ctrl[C_OFFS + t] + atomicAdd(&ctrl[C_CURS + t], 1);
    perm[i] = b;
}

__global__ void k_gather_x(const float* __restrict__ x, const int* __restrict__ perm, f16* __restrict__ Xp) {
    int i = blockIdx.x;
    int r = perm[i];
    for (int c = threadIdx.x; c < KP1; c += 256)
        Xp[(long)i * KP1 + c] = (c < D_) ? (f16)x[(long)r * D_ + c] : (f16)0.f;
}

// transpose-convert: src fp32 [T][K][N] -> dst f16 [T][Np][Kp], zero-padded
__global__ void k_convW(const float* __restrict__ src, f16* __restrict__ dst,
                        int K, int N, int Kp, int Np) {
    __shared__ float tile[32][33];
    int k0 = blockIdx.x * 32, n0 = blockIdx.y * 32, t = blockIdx.z;
    const float* s = src + (long)t * K * N;
    f16* d = dst + (long)t * Np * Kp;
    int tx = threadIdx.x, ty = threadIdx.y;
#pragma unroll
    for (int i = 0; i < 4; ++i) {
        int k = k0 + ty + i * 8;
        float v = (k < K && (n0 + tx) < N) ? s[(long)k * N + n0 + tx] : 0.f;
        tile[ty + i * 8][tx] = v;
    }
    __syncthreads();
#pragma unroll
    for (int i = 0; i < 4; ++i) {
        int n = n0 + ty + i * 8;
        if (n < Np) d[(long)n * Kp + k0 + tx] = (f16)tile[tx][ty + i * 8];
    }
}

// z = mu + exp(ls) * eps  (permuted rows)
__global__ void k_z(const float* __restrict__ mu, const float* __restrict__ ls,
                    const float* __restrict__ eps, const int* __restrict__ perm,
                    f16* __restrict__ Z) {
    long gid = (long)blockIdx.x * 256 + threadIdx.x;
    int i = (int)(gid >> 7), c = (int)(gid & 127);
    int r = perm[i];
    float m = mu[(long)r * L_ + c];
    float l = ls[(long)r * L_ + c];
    Z[(long)i * L_ + c] = (f16)(m + __expf(l) * eps[(long)r * L_ + c]);
}

// 128x128 tile, BK=64, 4 waves (2x2), each wave 64x64 via 4x4 frags of 16x16x32.
// A: [rows][K] f16 (row pitch == K). W: per-task [Np][K] f16 (row pitch == K).
// EPI 0: relu -> f16 out [row][H_]. EPI 1: mu/ls scatter fp32. EPI 2: sigmoid scatter fp32.
template <int EPI, bool GROUPED>
__global__ __launch_bounds__(256)
void k_gemm(const f16* __restrict__ A,
            const f16* __restrict__ W, long wstride,
            const float* __restrict__ bias, int bstride,
            int K, int N,
            f16* __restrict__ outF16,
            float* __restrict__ o0, float* __restrict__ o1,
            const int* __restrict__ ctrl, const int* __restrict__ perm) {
    __shared__ f16 sA[128 * 64];
    __shared__ f16 sB[128 * 64];
    int tid = threadIdx.x;
    int lane = tid & 63, wave = tid >> 6;
    int wm = wave >> 1, wn = wave & 1;
    int n0 = blockIdx.x * 128;

    int t, row0, mrows;
    if (GROUPED) {
        int nt = ctrl[C_NTILES];
        if ((int)blockIdx.y >= nt) return;
        t = ctrl[C_TTASK + blockIdx.y];
        row0 = ctrl[C_TROW + blockIdx.y];
        mrows = min(128, ctrl[C_OFFS + t + 1] - row0);
    } else {
        t = 0; row0 = blockIdx.y * 128; mrows = 128;
    }
    const f16* Wt = W + (long)t * wstride;
    const float* bt = bias + (long)t * bstride;

    f32x4 acc[4][4];
#pragma unroll
    for (int i = 0; i < 4; ++i)
#pragma unroll
        for (int j = 0; j < 4; ++j) acc[i][j] = (f32x4){0.f, 0.f, 0.f, 0.f};

    int nk = K >> 6;
    for (int kt = 0; kt < nk; ++kt) {
        int k0 = kt << 6;
        f16x8 ra[4], rb[4];
#pragma unroll
        for (int j = 0; j < 4; ++j) {
            int g = tid + 256 * j;
            int r = g >> 3, c = (g & 7) << 3;
            ra[j] = *(const f16x8*)(A + (long)(row0 + r) * K + k0 + c);
            rb[j] = *(const f16x8*)(Wt + (long)(n0 + r) * K + k0 + c);
        }
        __syncthreads();
#pragma unroll
        for (int j = 0; j < 4; ++j) {
            int g = tid + 256 * j;
            int r = g >> 3, c = (g & 7) << 3;
            *(f16x8*)(sA + r * 64 + c) = ra[j];
            *(f16x8*)(sB + r * 64 + c) = rb[j];
        }
        __syncthreads();
#pragma unroll
        for (int kk = 0; kk < 2; ++kk) {
            f16x8 af[4], bf[4];
            int ko = kk * 32 + ((lane >> 4) << 3);
#pragma unroll
            for (int mi = 0; mi < 4; ++mi)
                af[mi] = *(const f16x8*)(sA + (wm * 64 + mi * 16 + (lane & 15)) * 64 + ko);
#pragma unroll
            for (int nj = 0; nj < 4; ++nj)
                bf[nj] = *(const f16x8*)(sB + (wn * 64 + nj * 16 + (lane & 15)) * 64 + ko);
#pragma unroll
            for (int mi = 0; mi < 4; ++mi)
#pragma unroll
                for (int nj = 0; nj < 4; ++nj)
                    acc[mi][nj] = __builtin_amdgcn_mfma_f32_16x16x32_f16(af[mi], bf[nj], acc[mi][nj], 0, 0, 0);
        }
    }

    int cq = lane >> 4;
    int cr = lane & 15;
#pragma unroll
    for (int mi = 0; mi < 4; ++mi) {
#pragma unroll
        for (int nj = 0; nj < 4; ++nj) {
#pragma unroll
            for (int reg = 0; reg < 4; ++reg) {
                int rl = wm * 64 + mi * 16 + cq * 4 + reg;
                int cl = wn * 64 + nj * 16 + cr;
                if (rl >= mrows) continue;
                int gcol = n0 + cl;
                if (gcol >= N) continue;
                float v = acc[mi][nj][reg] + bt[gcol];
                int grow = row0 + rl;
                if (EPI == 0) {
                    outF16[(long)grow * H_ + gcol] = (f16)(v > 0.f ? v : 0.f);
                } else if (EPI == 1) {
                    int r = perm[grow];
                    if (gcol < L_) o0[(long)r * L_ + gcol] = v;
                    else o1[(long)r * L_ + (gcol - L_)] = v;
                } else {
                    int r = perm[grow];
                    o0[(long)r * D_ + gcol] = 1.f / (1.f + __expf(-v));
                }
            }
        }
    }
}

extern "C" void kernel_launch(void* const* d_in, const int* in_sizes, int n_in,
                              void* d_out, int out_size, void* d_ws, size_t ws_size,
                              hipStream_t stream) {
    const float* x   = (const float*)d_in[0];
    const float* eps = (const float*)d_in[1];
    const float* eW1 = (const float*)d_in[2];
    const float* eb1 = (const float*)d_in[3];
    const float* eW2 = (const float*)d_in[4];
    const float* eb2 = (const float*)d_in[5];
    const float* eW3 = (const float*)d_in[6];
    const float* eb3 = (const float*)d_in[7];
    const float* dW1 = (const float*)d_in[8];
    const float* db1 = (const float*)d_in[9];
    const float* dW2 = (const float*)d_in[10];
    const float* db2 = (const float*)d_in[11];
    const float* hW  = (const float*)d_in[12];
    const float* hb  = (const float*)d_in[13];
    const int* task  = (const int*)d_in[14];

    float* out = (float*)d_out;
    float* recon = out;
    float* mu = out + (size_t)B_ * D_;
    float* ls = mu + (size_t)B_ * L_;

    char* w = (char*)d_ws;
    size_t o = 0;
    auto alloc = [&](size_t bytes) -> char* {
        char* p = w + o;
        o = (o + bytes + 255) & ~(size_t)255;
        return p;
    };
    int* ctrl  = (int*)alloc(1024);
    int* perm  = (int*)alloc((size_t)B_ * 4);
    f16* Xp    = (f16*)alloc((size_t)(B_ + 128) * KP1 * 2);
    f16* H1    = (f16*)alloc((size_t)(B_ + 128) * H_ * 2);
    f16* H2    = (f16*)alloc((size_t)(B_ + 128) * H_ * 2);
    f16* Z     = (f16*)alloc((size_t)(B_ + 128) * L_ * 2);
    f16* Wt1   = (f16*)alloc((size_t)T_ * H_ * KP1 * 2);
    f16* Wt2   = (f16*)alloc((size_t)T_ * H_ * H_ * 2);
    f16* Wt3   = (f16*)alloc((size_t)T_ * 256 * H_ * 2);
    f16* WtD1  = (f16*)alloc((size_t)H_ * L_ * 2);
    f16* WtD2  = (f16*)alloc((size_t)H_ * H_ * 2);
    f16* WtH   = (f16*)alloc((size_t)T_ * NPH * H_ * 2);
    if (o > ws_size) return;  // workspace too small: fail loudly

    k_init<<<1, 64, 0, stream>>>(ctrl);
    k_count<<<B_ / 256, 256, 0, stream>>>(task, ctrl);
    k_scan<<<1, 1, 0, stream>>>(ctrl);
    k_scatter<<<B_ / 256, 256, 0, stream>>>(task, ctrl, perm);
    k_gather_x<<<B_, 256, 0, stream>>>(x, perm, Xp);

    k_convW<<<dim3(KP1 / 32, H_ / 32, T_), dim3(32, 8), 0, stream>>>(eW1, Wt1, D_, H_, KP1, H_);
    k_convW<<<dim3(H_ / 32, H_ / 32, T_), dim3(32, 8), 0, stream>>>(eW2, Wt2, H_, H_, H_, H_);
    k_convW<<<dim3(H_ / 32, 256 / 32, T_), dim3(32, 8), 0, stream>>>(eW3, Wt3, H_, 256, H_, 256);
    k_convW<<<dim3(L_ / 32, H_ / 32, 1), dim3(32, 8), 0, stream>>>(dW1, WtD1, L_, H_, L_, H_);
    k_convW<<<dim3(H_ / 32, H_ / 32, 1), dim3(32, 8), 0, stream>>>(dW2, WtD2, H_, H_, H_, H_);
    k_convW<<<dim3(H_ / 32, NPH / 32, T_), dim3(32, 8), 0, stream>>>(hW, WtH, H_, D_, H_, NPH);

    // encoder layer 1: Xp(KP1) @ Wt1 -> relu -> H1
    k_gemm<0, true><<<dim3(H_ / 128, MAXTILES), 256, 0, stream>>>(
        Xp, Wt1, (long)H_ * KP1, eb1, H_, KP1, H_, H1, nullptr, nullptr, ctrl, perm);
    // encoder layer 2: H1 @ Wt2 -> relu -> H2
    k_gemm<0, true><<<dim3(H_ / 128, MAXTILES), 256, 0, stream>>>(
        H1, Wt2, (long)H_ * H_, eb2, H_, H_, H_, H2, nullptr, nullptr, ctrl, perm);
    // encoder layer 3: H2 @ Wt3 -> mu/ls (scatter fp32 to d_out)
    k_gemm<1, true><<<dim3(256 / 128, MAXTILES), 256, 0, stream>>>(
        H2, Wt3, (long)256 * H_, eb3, 256, H_, 256, nullptr, mu, ls, ctrl, perm);
    // z = mu + exp(ls)*eps (fp16, permuted)
    k_z<<<(B_ * L_) / 256, 256, 0, stream>>>(mu, ls, eps, perm, Z);
    // decoder layer 1: Z(128) @ WtD1 -> relu -> H1 (reuse)
    k_gemm<0, false><<<dim3(H_ / 128, B_ / 128), 256, 0, stream>>>(
        Z, WtD1, 0, db1, 0, L_, H_, H1, nullptr, nullptr, ctrl, perm);
    // decoder layer 2: H1 @ WtD2 -> relu -> H2 (reuse)
    k_gemm<0, false><<<dim3(H_ / 128, B_ / 128), 256, 0, stream>>>(
        H1, WtD2, 0, db2, 0, H_, H_, H2, nullptr, nullptr, ctrl, perm);
    // head: H2 @ WtH -> sigmoid -> recon (scatter fp32)
    k_gemm<2, true><<<dim3(NPH / 128, MAXTILES), 256, 0, stream>>>(
        H2, WtH, (long)NPH * H_, hb, D_, H_, D_, nullptr, recon, nullptr, ctrl, perm);
}